// Round 3
// baseline (58269.934 us; speedup 1.0000x reference)
//
#include <hip/hip_runtime.h>

// Problem: B=256, T=512, F=16, H=256, L=2 LSTM + gather(lengths-1) + ReLU + FC.
//
// Structure: 192 persistent blocks = 8 batch-groups(32b) x (8 L0-blocks(32u) +
// 16 L1-blocks(16u)). Weight slices live in LDS (loaded once). Per step only
// h crosses blocks, via L3 (system-scope relaxed atomics = sc0 sc1 write/read-
// through; NO threadfence, NO RMW flags). Ring depth 4 per h stream.
//
// ws layout (float offsets), weights repacked [k][unit][gate i,f,g,o]:
#define OFF_IH0 0            //  [16][256][4]
#define OFF_HH0 16384        //  [256][256][4]
#define OFF_IH1 278528       //  [256][256][4]
#define OFF_HH1 540672       //  [256][256][4]
#define OFF_B0  802816       //  [256][4] = b_ih0+b_hh0
#define OFF_B1  803840       //  [256][4]
#define OFF_H0RING 804864    //  [8g][4 slot][256u][32b]
#define OFF_H1RING 1067008   //  [8g][4 slot][256u][32b]
#define OFF_HLAST  1329152   //  [256b][256u]
#define OFF_FLAGS  1394688   //  ints: h0flag [8g][8p]*16; then h1flag [8g][16p]*16
#define WS_FLOATS  1398784   //  5.6 MB

#define SMEM_BYTES 147456    // L0: 128K whh + 8K wih + 8K h-stage; L1: 128K w + 16K stage

__global__ __launch_bounds__(256) void prep_kernel(
    const float* __restrict__ w_ih0, const float* __restrict__ w_hh0,
    const float* __restrict__ b_ih0, const float* __restrict__ b_hh0,
    const float* __restrict__ w_ih1, const float* __restrict__ w_hh1,
    const float* __restrict__ b_ih1, const float* __restrict__ b_hh1,
    float* __restrict__ ws) {
  int idx = blockIdx.x * blockDim.x + threadIdx.x;  // [0, 262144)
  int c = idx & 3;
  int m = (idx >> 2) & 255;
  int k = idx >> 10;
  int j = c * 256 + m;
  if (k < 16) ws[OFF_IH0 + idx] = w_ih0[j * 16 + k];
  ws[OFF_HH0 + idx] = w_hh0[j * 256 + k];
  ws[OFF_IH1 + idx] = w_ih1[j * 256 + k];
  ws[OFF_HH1 + idx] = w_hh1[j * 256 + k];
  if (idx < 1024) {
    ws[OFF_B0 + idx] = b_ih0[j] + b_hh0[j];
    ws[OFF_B1 + idx] = b_ih1[j] + b_hh1[j];
  }
}

__device__ __forceinline__ float sigf(float x) {
  return __fdividef(1.f, 1.f + __expf(-x));
}
__device__ __forceinline__ float tanhf_fast(float x) {
  float ax = fabsf(x);
  float e = __expf(-2.f * ax);
  float t = __fdividef(1.f - e, 1.f + e);
  return copysignf(t, x);
}
__device__ __forceinline__ float4 f4fma(float4 a, float4 w, float s) {
  a.x = fmaf(w.x, s, a.x);
  a.y = fmaf(w.y, s, a.y);
  a.z = fmaf(w.z, s, a.z);
  a.w = fmaf(w.w, s, a.w);
  return a;
}

// L3-coherent (system scope, relaxed) 8-byte ops: compile to
// global_{load,store}_dwordx2 ... sc0 sc1 — bypass L1/L2 both ways.
__device__ __forceinline__ void sys_store_f2(float* p, float a, float b) {
  unsigned long long v = (unsigned long long)__float_as_uint(a) |
                         ((unsigned long long)__float_as_uint(b) << 32);
  __hip_atomic_store((unsigned long long*)p, v, __ATOMIC_RELAXED,
                     __HIP_MEMORY_SCOPE_SYSTEM);
}
__device__ __forceinline__ float2 sys_load_f2(const float* p) {
  unsigned long long v = __hip_atomic_load((const unsigned long long*)p,
                                           __ATOMIC_RELAXED,
                                           __HIP_MEMORY_SCOPE_SYSTEM);
  float2 r;
  r.x = __uint_as_float((unsigned)v);
  r.y = __uint_as_float((unsigned)(v >> 32));
  return r;
}

// Wait until flag[i] >= target for i in [0,n). One lane polls one flag word
// (flags are 64B apart, store-only by producers — no RMW contention).
__device__ __forceinline__ void wait_flags(int* f, int n, int target) {
  if ((int)threadIdx.x < n) {
    int guard = 0;
    while (__hip_atomic_load(f + threadIdx.x * 16, __ATOMIC_RELAXED,
                             __HIP_MEMORY_SCOPE_SYSTEM) < target) {
      __builtin_amdgcn_s_sleep(1);
      if (++guard > (1 << 22)) break;  // fail loud (wrong result), not hang
    }
  }
  __syncthreads();
}

__global__ __launch_bounds__(256) void lstm_persistent(
    float* __restrict__ ws, const float* __restrict__ x,
    const int* __restrict__ lengths) {
  extern __shared__ float smem[];
  __shared__ int s_tmax;
  const int tid = threadIdx.x;
  const int g = blockIdx.x & 7;
  const int r = blockIdx.x >> 3;  // 0..7: L0 slice; 8..23: L1 slice
  const int b0 = g * 32;
  float* h0ring = ws + OFF_H0RING + g * 32768;  // [4][8192]
  float* h1ring = ws + OFF_H1RING + g * 32768;
  int* h0flag = (int*)(ws + OFF_FLAGS) + g * 128;         // 8 producers
  int* h1flag = (int*)(ws + OFF_FLAGS) + 1024 + g * 256;  // 16 producers

  if (tid == 0) {
    int m = 1;
    for (int i = 0; i < 32; ++i) m = max(m, lengths[b0 + i]);
    s_tmax = m;
  }

  if (r < 8) {
    // ============ layer 0: 32 units x 32 batches ============
    const int u = tid >> 3, bq = tid & 7;
    const int u0 = r * 32;
    float4* lwhh = (float4*)smem;           // [256][32]
    float4* lwih = lwhh + 8192;             // [16][32]
    float* hst = (float*)(lwih + 512);      // [2][32][32] h-stage
    const float4* ghh = (const float4*)(ws + OFF_HH0);
    const float4* gih = (const float4*)(ws + OFF_IH0);
    for (int e = tid; e < 8192; e += 256)
      lwhh[e] = ghh[(e >> 5) * 256 + u0 + (e & 31)];
    for (int e = tid; e < 512; e += 256)
      lwih[e] = gih[(e >> 5) * 256 + u0 + (e & 31)];
    const float4 bias = ((const float4*)(ws + OFF_B0))[u0 + u];
    __syncthreads();
    const int tmax = s_tmax;
    float c0 = 0.f, c1 = 0.f, c2 = 0.f, c3 = 0.f;
    const float4* xb0 = (const float4*)x + (size_t)(b0 + bq * 4 + 0) * 2048;
    const float4* xb1 = (const float4*)x + (size_t)(b0 + bq * 4 + 1) * 2048;
    const float4* xb2 = (const float4*)x + (size_t)(b0 + bq * 4 + 2) * 2048;
    const float4* xb3 = (const float4*)x + (size_t)(b0 + bq * 4 + 3) * 2048;
    const int si = (tid >> 3) * 32 + (tid & 7) * 4;  // stage idx: k-row, b-col

    for (int t = 0; t < tmax; ++t) {
      float4 a0 = bias, a1 = bias, a2 = bias, a3 = bias;
      // x-part (no dependence on peers — overlaps their tail)
      #pragma unroll
      for (int i4 = 0; i4 < 4; ++i4) {
        float4 xv0 = xb0[t * 4 + i4], xv1 = xb1[t * 4 + i4];
        float4 xv2 = xb2[t * 4 + i4], xv3 = xb3[t * 4 + i4];
        const float x0[4] = {xv0.x, xv0.y, xv0.z, xv0.w};
        const float x1[4] = {xv1.x, xv1.y, xv1.z, xv1.w};
        const float x2[4] = {xv2.x, xv2.y, xv2.z, xv2.w};
        const float x3[4] = {xv3.x, xv3.y, xv3.z, xv3.w};
        #pragma unroll
        for (int ii = 0; ii < 4; ++ii) {
          float4 w = lwih[(i4 * 4 + ii) * 32 + u];
          a0 = f4fma(a0, w, x0[ii]);
          a1 = f4fma(a1, w, x1[ii]);
          a2 = f4fma(a2, w, x2[ii]);
          a3 = f4fma(a3, w, x3[ii]);
        }
      }
      // own-cohort h0[t-1] ready (t=0: slot 3 pre-zeroed)
      wait_flags(h0flag, 8, t);
      const float* slot = h0ring + ((t + 3) & 3) * 8192;
      float2 p0 = sys_load_f2(slot + si);
      float2 p1 = sys_load_f2(slot + si + 2);
      for (int c = 0; c < 8; ++c) {
        float* sb = hst + (c & 1) * 1024;
        *(float2*)(sb + si) = p0;
        *(float2*)(sb + si + 2) = p1;
        if (c < 7) {
          p0 = sys_load_f2(slot + (c + 1) * 1024 + si);
          p1 = sys_load_f2(slot + (c + 1) * 1024 + si + 2);
        }
        __syncthreads();
        #pragma unroll 8
        for (int kk = 0; kk < 32; ++kk) {
          float4 h4 = *(const float4*)(sb + kk * 32 + bq * 4);
          float4 w = lwhh[(c * 32 + kk) * 32 + u];
          a0 = f4fma(a0, w, h4.x);
          a1 = f4fma(a1, w, h4.y);
          a2 = f4fma(a2, w, h4.z);
          a3 = f4fma(a3, w, h4.w);
        }
        __syncthreads();
      }
      float4 hv;
      c0 = sigf(a0.y) * c0 + sigf(a0.x) * tanhf_fast(a0.z);
      hv.x = sigf(a0.w) * tanhf_fast(c0);
      c1 = sigf(a1.y) * c1 + sigf(a1.x) * tanhf_fast(a1.z);
      hv.y = sigf(a1.w) * tanhf_fast(c1);
      c2 = sigf(a2.y) * c2 + sigf(a2.x) * tanhf_fast(a2.z);
      hv.z = sigf(a2.w) * tanhf_fast(c2);
      c3 = sigf(a3.y) * c3 + sigf(a3.x) * tanhf_fast(a3.z);
      hv.w = sigf(a3.w) * tanhf_fast(c3);
      // overwrite h0[t-4]: all 16 consumers must have finished step t-4
      if (t >= 4) wait_flags(h1flag, 16, t - 3);
      float* wp = h0ring + (t & 3) * 8192 + (u0 + u) * 32 + bq * 4;
      sys_store_f2(wp, hv.x, hv.y);
      sys_store_f2(wp + 2, hv.z, hv.w);
      __syncthreads();  // emits vmcnt(0): all waves' h-stores drained
      if (tid == 0)
        __hip_atomic_store(h0flag + r * 16, t + 1, __ATOMIC_RELAXED,
                           __HIP_MEMORY_SCOPE_SYSTEM);
    }
  } else {
    // ============ layer 1: 16 units x 32 batches ============
    const int s = r - 8;
    const int u = tid >> 4, bp = tid & 15;
    const int u0 = s * 16;
    float4* lwih = (float4*)smem;       // [256][16]
    float4* lwhh = lwih + 4096;         // [256][16]
    float* h0st = (float*)(lwhh + 4096);  // [2][32][32]
    float* h1st = h0st + 2048;            // [2][32][32]
    const float4* gih = (const float4*)(ws + OFF_IH1);
    const float4* ghh = (const float4*)(ws + OFF_HH1);
    for (int e = tid; e < 4096; e += 256) {
      lwih[e] = gih[(e >> 4) * 256 + u0 + (e & 15)];
      lwhh[e] = ghh[(e >> 4) * 256 + u0 + (e & 15)];
    }
    const float4 bias = ((const float4*)(ws + OFF_B1))[u0 + u];
    __syncthreads();
    const int tmax = s_tmax;
    const int bA = b0 + bp * 2, bB = bA + 1;
    const int lenA = lengths[bA], lenB = lengths[bB];
    float cA = 0.f, cB = 0.f;
    const int si = (tid >> 3) * 32 + (tid & 7) * 4;

    for (int t = 0; t < tmax; ++t) {
      wait_flags(h1flag, 16, t);      // peers' h1[t-1] (also guards ring reuse)
      wait_flags(h0flag, 8, t + 1);   // L0 finished step t
      const float* s0 = h0ring + (t & 3) * 8192;
      const float* s1 = h1ring + ((t + 3) & 3) * 8192;
      float4 aA = bias, aB = bias;
      float2 q0 = sys_load_f2(s0 + si);
      float2 q1 = sys_load_f2(s0 + si + 2);
      float2 q2 = sys_load_f2(s1 + si);
      float2 q3 = sys_load_f2(s1 + si + 2);
      for (int c = 0; c < 8; ++c) {
        float* b0s = h0st + (c & 1) * 1024;
        float* b1s = h1st + (c & 1) * 1024;
        *(float2*)(b0s + si) = q0;
        *(float2*)(b0s + si + 2) = q1;
        *(float2*)(b1s + si) = q2;
        *(float2*)(b1s + si + 2) = q3;
        if (c < 7) {
          int off = (c + 1) * 1024 + si;
          q0 = sys_load_f2(s0 + off);
          q1 = sys_load_f2(s0 + off + 2);
          q2 = sys_load_f2(s1 + off);
          q3 = sys_load_f2(s1 + off + 2);
        }
        __syncthreads();
        #pragma unroll 8
        for (int kk = 0; kk < 32; ++kk) {
          float2 h0v = *(const float2*)(b0s + kk * 32 + bp * 2);
          float2 h1v = *(const float2*)(b1s + kk * 32 + bp * 2);
          float4 wi = lwih[(c * 32 + kk) * 16 + u];
          float4 wh = lwhh[(c * 32 + kk) * 16 + u];
          aA = f4fma(aA, wi, h0v.x);
          aB = f4fma(aB, wi, h0v.y);
          aA = f4fma(aA, wh, h1v.x);
          aB = f4fma(aB, wh, h1v.y);
        }
        __syncthreads();
      }
      float hA, hB;
      cA = sigf(aA.y) * cA + sigf(aA.x) * tanhf_fast(aA.z);
      hA = sigf(aA.w) * tanhf_fast(cA);
      cB = sigf(aB.y) * cB + sigf(aB.x) * tanhf_fast(aB.z);
      hB = sigf(aB.w) * tanhf_fast(cB);
      sys_store_f2(h1ring + (t & 3) * 8192 + (u0 + u) * 32 + bp * 2, hA, hB);
      if (t == lenA - 1) ws[OFF_HLAST + (size_t)bA * 256 + u0 + u] = hA;
      if (t == lenB - 1) ws[OFF_HLAST + (size_t)bB * 256 + u0 + u] = hB;
      __syncthreads();  // emits vmcnt(0): h-store drained in every wave
      if (tid == 0)
        __hip_atomic_store(h1flag + s * 16, t + 1, __ATOMIC_RELAXED,
                           __HIP_MEMORY_SCOPE_SYSTEM);
    }
  }
}

__global__ __launch_bounds__(256) void fc_kernel(
    const float* __restrict__ ws, const float* __restrict__ fc_w,
    const float* __restrict__ fc_b, float* __restrict__ out) {
  __shared__ float red[256];
  const int tid = threadIdx.x;
  const int b = blockIdx.x;
  red[tid] = fmaxf(ws[OFF_HLAST + (size_t)b * 256 + tid], 0.f) * fc_w[tid];
  __syncthreads();
  #pragma unroll
  for (int s = 128; s > 0; s >>= 1) {
    if (tid < s) red[tid] += red[tid + s];
    __syncthreads();
  }
  if (tid == 0) out[b] = red[0] + fc_b[0];
}

extern "C" void kernel_launch(void* const* d_in, const int* in_sizes, int n_in,
                              void* d_out, int out_size, void* d_ws, size_t ws_size,
                              hipStream_t stream) {
  const float* x     = (const float*)d_in[0];
  const int*   lens  = (const int*)d_in[1];
  const float* w_ih0 = (const float*)d_in[2];
  const float* w_hh0 = (const float*)d_in[3];
  const float* b_ih0 = (const float*)d_in[4];
  const float* b_hh0 = (const float*)d_in[5];
  const float* w_ih1 = (const float*)d_in[6];
  const float* w_hh1 = (const float*)d_in[7];
  const float* b_ih1 = (const float*)d_in[8];
  const float* b_hh1 = (const float*)d_in[9];
  const float* fc_w  = (const float*)d_in[10];
  const float* fc_b  = (const float*)d_in[11];
  float* out = (float*)d_out;
  float* ws  = (float*)d_ws;

  hipLaunchKernelGGL(prep_kernel, dim3(1024), dim3(256), 0, stream,
                     w_ih0, w_hh0, b_ih0, b_hh0, w_ih1, w_hh1, b_ih1, b_hh1, ws);
  // zero rings (h[-1]=0), hlast, flags (ws is 0xAA-poisoned before each run)
  hipMemsetAsync((char*)d_ws + (size_t)OFF_H0RING * 4, 0,
                 (size_t)(WS_FLOATS - OFF_H0RING) * 4, stream);

  hipFuncSetAttribute(reinterpret_cast<const void*>(lstm_persistent),
                      hipFuncAttributeMaxDynamicSharedMemorySize, SMEM_BYTES);
  void* args[] = {(void*)&ws, (void*)&x, (void*)&lens};
  hipLaunchCooperativeKernel(reinterpret_cast<const void*>(lstm_persistent),
                             dim3(192), dim3(256), args, SMEM_BYTES, stream);

  hipLaunchKernelGGL(fc_kernel, dim3(256), dim3(256), 0, stream,
                     ws, fc_w, fc_b, out);
}

// Round 4
// 14292.911 us; speedup vs baseline: 4.0768x; 4.0768x over previous
//
#include <hip/hip_runtime.h>

// B=256, T=512, F=16, H=256, L=2 LSTM + gather(len-1) + ReLU + FC(256->1).
//
// Round-4 structure: NO intra-kernel cross-block communication (R2/R3 showed
// memory handshakes cost 50-100 us/step). Phases via kernel launches:
//   prep: pack weights [k][unit][gate i,f,g,o] (float4 per (k,u))
//   4 chunks of Tc=128 steps: { lstm_l0 chunk -> h0 buffer; lstm_l1 chunk }
//   fc: final gather+ReLU+dot
// Recurrence kernels: 86 blocks x 512 thr, G=3 batches/block, h in LDS
// (block-local), cell state in regs, weights streamed from L2-resident set
// with 8-deep dwordx4 prefetch; k-split over 2 thread-halves.

#define Tc 128

#define OFF_IH0 0            // [16][256][4]
#define OFF_HH0 16384        // [256][256][4]
#define OFF_IH1 278528       // [256][256][4]
#define OFF_HH1 540672       // [256][256][4]
#define OFF_B0  802816       // [256][4] = b_ih0+b_hh0
#define OFF_B1  803840       // [256][4]
#define OFF_H0C 804864       // h0 chunk [258 b][128 tc][256 u]
#define OFF_C0S 9259008      // [258][256] layer-0 cell state
#define OFF_C1S 9325056      // [258][256] layer-1 cell state
#define OFF_H1S 9391104      // [258][256] layer-1 h state
#define OFF_HLAST 9457152    // [258][256]
#define WS_FLOATS 9523200    // 38.1 MB

__global__ __launch_bounds__(256) void prep_kernel(
    const float* __restrict__ w_ih0, const float* __restrict__ w_hh0,
    const float* __restrict__ b_ih0, const float* __restrict__ b_hh0,
    const float* __restrict__ w_ih1, const float* __restrict__ w_hh1,
    const float* __restrict__ b_ih1, const float* __restrict__ b_hh1,
    float* __restrict__ ws) {
  int idx = blockIdx.x * blockDim.x + threadIdx.x;  // [0, 262144)
  int c = idx & 3;
  int m = (idx >> 2) & 255;
  int k = idx >> 10;
  int j = c * 256 + m;  // gate row in [0,1024)
  if (k < 16) ws[OFF_IH0 + idx] = w_ih0[j * 16 + k];
  ws[OFF_HH0 + idx] = w_hh0[j * 256 + k];
  ws[OFF_IH1 + idx] = w_ih1[j * 256 + k];
  ws[OFF_HH1 + idx] = w_hh1[j * 256 + k];
  if (idx < 1024) {
    ws[OFF_B0 + idx] = b_ih0[j] + b_hh0[j];
    ws[OFF_B1 + idx] = b_ih1[j] + b_hh1[j];
  }
}

__device__ __forceinline__ float sigf(float x) {
  return __fdividef(1.f, 1.f + __expf(-x));
}
__device__ __forceinline__ float tanhf_fast(float x) {
  float ax = fabsf(x);
  float e = __expf(-2.f * ax);
  float t = __fdividef(1.f - e, 1.f + e);
  return copysignf(t, x);
}
__device__ __forceinline__ float4 f4fma(float4 a, float4 w, float s) {
  a.x = fmaf(w.x, s, a.x);
  a.y = fmaf(w.y, s, a.y);
  a.z = fmaf(w.z, s, a.z);
  a.w = fmaf(w.w, s, a.w);
  return a;
}

// ---------------- layer 0 recurrence, one chunk of Tc steps ----------------
__global__ __launch_bounds__(512, 2) void lstm_l0(
    float* __restrict__ ws, const float* __restrict__ x,
    const int* __restrict__ lengths, int t0) {
  __shared__ __align__(16) float4 hdb[2][256];      // h0[t-1..t], [k] x 3 batches
  __shared__ __align__(16) float scratch[256][12];  // half1 partial gates
  __shared__ __align__(16) float xs[3][16];
  const int tid = threadIdx.x;
  const int kh = tid >> 8;   // k-half: 0 -> k 0..127, 1 -> 128..255
  const int u = tid & 255;   // hidden unit
  const int bg = blockIdx.x * 3;

  int len[3];
  #pragma unroll
  for (int b = 0; b < 3; ++b)
    len[b] = (bg + b < 256) ? lengths[bg + b] : 1;
  const int tmaxb = max(len[0], max(len[1], len[2]));
  if (t0 >= tmaxb) return;
  const int tend = min(Tc, tmaxb - t0);

  const float4* wq = (const float4*)(ws + OFF_HH0) + kh * 128 * 256 + u;
  const float4* wih = (const float4*)(ws + OFF_IH0) + kh * 8 * 256 + u;
  const float4 bias = ((const float4*)(ws + OFF_B0))[u];

  float c[3] = {0.f, 0.f, 0.f};
  if (kh == 0) {
    float4 hp = make_float4(0.f, 0.f, 0.f, 0.f);
    if (t0 > 0) {
      hp.x = ws[OFF_H0C + ((size_t)(bg + 0) * Tc + (Tc - 1)) * 256 + u];
      hp.y = ws[OFF_H0C + ((size_t)(bg + 1) * Tc + (Tc - 1)) * 256 + u];
      hp.z = ws[OFF_H0C + ((size_t)(bg + 2) * Tc + (Tc - 1)) * 256 + u];
      #pragma unroll
      for (int b = 0; b < 3; ++b) c[b] = ws[OFF_C0S + (bg + b) * 256 + u];
    }
    hdb[0][u] = hp;
  }
  if (tid < 48) {  // stage x[*, t0, *]
    int b = tid >> 4, i = tid & 15;
    int bb = min(bg + b, 255);
    xs[b][i] = x[(size_t)bb * 8192 + t0 * 16 + i];
  }
  __syncthreads();

  for (int tc = 0; tc < tend; ++tc) {
    const int t = t0 + tc;
    float4 a0, a1, a2;
    if (kh == 0) { a0 = bias; a1 = bias; a2 = bias; }
    else { a0 = make_float4(0,0,0,0); a1 = a0; a2 = a0; }

    // x-part: 8 of 16 inputs per half (w_ih0 stream is 64 KB, L2/L1-hot)
    #pragma unroll
    for (int ii = 0; ii < 8; ++ii) {
      float4 w = wih[ii * 256];
      a0 = f4fma(a0, w, xs[0][kh * 8 + ii]);
      a1 = f4fma(a1, w, xs[1][kh * 8 + ii]);
      a2 = f4fma(a2, w, xs[2][kh * 8 + ii]);
    }

    // h-part: 128 k per half, 8-deep prefetch of the weight stream
    {
      const float4* hrow = &hdb[tc & 1][kh * 128];
      float4 wb[8];
      #pragma unroll
      for (int p = 0; p < 8; ++p) wb[p] = wq[p * 256];
      for (int jc = 0; jc < 128; jc += 8) {
        float4 wn[8];
        if (jc + 8 < 128) {
          #pragma unroll
          for (int p = 0; p < 8; ++p) wn[p] = wq[(jc + 8 + p) * 256];
        }
        #pragma unroll
        for (int p = 0; p < 8; ++p) {
          float4 h4 = hrow[jc + p];  // same addr all lanes -> broadcast
          a0 = f4fma(a0, wb[p], h4.x);
          a1 = f4fma(a1, wb[p], h4.y);
          a2 = f4fma(a2, wb[p], h4.z);
        }
        #pragma unroll
        for (int p = 0; p < 8; ++p) wb[p] = wn[p];
      }
    }

    if (kh == 1) {
      float4* s4 = (float4*)scratch[u];
      s4[0] = a0; s4[1] = a1; s4[2] = a2;
    }
    __syncthreads();

    if (kh == 0) {
      const float4* s4 = (const float4*)scratch[u];
      a0 = f4fma(a0, s4[0], 1.f);
      a1 = f4fma(a1, s4[1], 1.f);
      a2 = f4fma(a2, s4[2], 1.f);
      float h[3];
      float4 A[3] = {a0, a1, a2};
      #pragma unroll
      for (int b = 0; b < 3; ++b) {
        float ig = sigf(A[b].x), fg = sigf(A[b].y);
        float gg = tanhf_fast(A[b].z), og = sigf(A[b].w);
        c[b] = fg * c[b] + ig * gg;
        h[b] = og * tanhf_fast(c[b]);
      }
      hdb[(tc + 1) & 1][u] = make_float4(h[0], h[1], h[2], 0.f);
      #pragma unroll
      for (int b = 0; b < 3; ++b)
        ws[OFF_H0C + ((size_t)(bg + b) * Tc + tc) * 256 + u] = h[b];
    } else if (tid >= 256 && tid < 304) {  // stage x for t+1
      int bi = tid - 256, b = bi >> 4, i = bi & 15;
      int bb = min(bg + b, 255);
      int tn = min(t + 1, 511);
      xs[b][i] = x[(size_t)bb * 8192 + tn * 16 + i];
    }
    __syncthreads();
  }

  if (kh == 0) {
    #pragma unroll
    for (int b = 0; b < 3; ++b) ws[OFF_C0S + (bg + b) * 256 + u] = c[b];
  }
}

// ---------------- layer 1 recurrence, one chunk of Tc steps ----------------
// gates = W_ih1 @ h0[t] + W_hh1 @ h1[t-1] + bias (input projection folded in)
__global__ __launch_bounds__(512, 2) void lstm_l1(
    float* __restrict__ ws, const int* __restrict__ lengths, int t0) {
  __shared__ __align__(16) float4 h1db[2][256];
  __shared__ __align__(16) float4 h0db[2][256];
  __shared__ __align__(16) float scratch[256][12];
  const int tid = threadIdx.x;
  const int kh = tid >> 8;
  const int u = tid & 255;
  const int bg = blockIdx.x * 3;

  int len[3];
  #pragma unroll
  for (int b = 0; b < 3; ++b)
    len[b] = (bg + b < 256) ? lengths[bg + b] : 1;
  const int tmaxb = max(len[0], max(len[1], len[2]));
  if (t0 >= tmaxb) return;
  const int tend = min(Tc, tmaxb - t0);

  const float4* wi = (const float4*)(ws + OFF_IH1) + kh * 128 * 256 + u;
  const float4* wh = (const float4*)(ws + OFF_HH1) + kh * 128 * 256 + u;
  const float4 bias = ((const float4*)(ws + OFF_B1))[u];

  float c[3] = {0.f, 0.f, 0.f};
  float h[3] = {0.f, 0.f, 0.f};
  if (kh == 0) {
    float4 hp = make_float4(0.f, 0.f, 0.f, 0.f);
    if (t0 > 0) {
      hp.x = ws[OFF_H1S + (bg + 0) * 256 + u];
      hp.y = ws[OFF_H1S + (bg + 1) * 256 + u];
      hp.z = ws[OFF_H1S + (bg + 2) * 256 + u];
      #pragma unroll
      for (int b = 0; b < 3; ++b) c[b] = ws[OFF_C1S + (bg + b) * 256 + u];
    }
    h1db[0][u] = hp;
    // stage h0[t0]
    float4 h0p;
    h0p.x = ws[OFF_H0C + ((size_t)(bg + 0) * Tc + 0) * 256 + u];
    h0p.y = ws[OFF_H0C + ((size_t)(bg + 1) * Tc + 0) * 256 + u];
    h0p.z = ws[OFF_H0C + ((size_t)(bg + 2) * Tc + 0) * 256 + u];
    h0p.w = 0.f;
    h0db[0][u] = h0p;
  }
  __syncthreads();

  for (int tc = 0; tc < tend; ++tc) {
    const int t = t0 + tc;
    float4 a0, a1, a2;
    if (kh == 0) { a0 = bias; a1 = bias; a2 = bias; }
    else { a0 = make_float4(0,0,0,0); a1 = a0; a2 = a0; }

    {
      const float4* h0row = &h0db[tc & 1][kh * 128];
      const float4* h1row = &h1db[tc & 1][kh * 128];
      float4 wbi[4], wbh[4];
      #pragma unroll
      for (int p = 0; p < 4; ++p) { wbi[p] = wi[p * 256]; wbh[p] = wh[p * 256]; }
      for (int jc = 0; jc < 128; jc += 4) {
        float4 wni[4], wnh[4];
        if (jc + 4 < 128) {
          #pragma unroll
          for (int p = 0; p < 4; ++p) {
            wni[p] = wi[(jc + 4 + p) * 256];
            wnh[p] = wh[(jc + 4 + p) * 256];
          }
        }
        #pragma unroll
        for (int p = 0; p < 4; ++p) {
          float4 h0v = h0row[jc + p];
          float4 h1v = h1row[jc + p];
          a0 = f4fma(a0, wbi[p], h0v.x);
          a1 = f4fma(a1, wbi[p], h0v.y);
          a2 = f4fma(a2, wbi[p], h0v.z);
          a0 = f4fma(a0, wbh[p], h1v.x);
          a1 = f4fma(a1, wbh[p], h1v.y);
          a2 = f4fma(a2, wbh[p], h1v.z);
        }
        #pragma unroll
        for (int p = 0; p < 4; ++p) { wbi[p] = wni[p]; wbh[p] = wnh[p]; }
      }
    }

    if (kh == 1) {
      float4* s4 = (float4*)scratch[u];
      s4[0] = a0; s4[1] = a1; s4[2] = a2;
      // prefetch h0[t+1] into the other LDS buffer
      if (tc + 1 < tend) {
        float4 h0n;
        h0n.x = ws[OFF_H0C + ((size_t)(bg + 0) * Tc + tc + 1) * 256 + u];
        h0n.y = ws[OFF_H0C + ((size_t)(bg + 1) * Tc + tc + 1) * 256 + u];
        h0n.z = ws[OFF_H0C + ((size_t)(bg + 2) * Tc + tc + 1) * 256 + u];
        h0n.w = 0.f;
        h0db[(tc + 1) & 1][u] = h0n;
      }
    }
    __syncthreads();

    if (kh == 0) {
      const float4* s4 = (const float4*)scratch[u];
      a0 = f4fma(a0, s4[0], 1.f);
      a1 = f4fma(a1, s4[1], 1.f);
      a2 = f4fma(a2, s4[2], 1.f);
      float4 A[3] = {a0, a1, a2};
      #pragma unroll
      for (int b = 0; b < 3; ++b) {
        float ig = sigf(A[b].x), fg = sigf(A[b].y);
        float gg = tanhf_fast(A[b].z), og = sigf(A[b].w);
        c[b] = fg * c[b] + ig * gg;
        h[b] = og * tanhf_fast(c[b]);
        if (t == len[b] - 1) ws[OFF_HLAST + (bg + b) * 256 + u] = h[b];
      }
      h1db[(tc + 1) & 1][u] = make_float4(h[0], h[1], h[2], 0.f);
    }
    __syncthreads();
  }

  if (kh == 0) {
    #pragma unroll
    for (int b = 0; b < 3; ++b) {
      ws[OFF_C1S + (bg + b) * 256 + u] = c[b];
      ws[OFF_H1S + (bg + b) * 256 + u] = h[b];
    }
  }
}

// ---------------- FC epilogue ----------------
__global__ __launch_bounds__(256) void fc_kernel(
    const float* __restrict__ ws, const float* __restrict__ fc_w,
    const float* __restrict__ fc_b, float* __restrict__ out) {
  __shared__ float red[256];
  const int tid = threadIdx.x;
  const int b = blockIdx.x;
  red[tid] = fmaxf(ws[OFF_HLAST + b * 256 + tid], 0.f) * fc_w[tid];
  __syncthreads();
  #pragma unroll
  for (int s = 128; s > 0; s >>= 1) {
    if (tid < s) red[tid] += red[tid + s];
    __syncthreads();
  }
  if (tid == 0) out[b] = red[0] + fc_b[0];
}

extern "C" void kernel_launch(void* const* d_in, const int* in_sizes, int n_in,
                              void* d_out, int out_size, void* d_ws, size_t ws_size,
                              hipStream_t stream) {
  const float* x     = (const float*)d_in[0];
  const int*   lens  = (const int*)d_in[1];
  const float* w_ih0 = (const float*)d_in[2];
  const float* w_hh0 = (const float*)d_in[3];
  const float* b_ih0 = (const float*)d_in[4];
  const float* b_hh0 = (const float*)d_in[5];
  const float* w_ih1 = (const float*)d_in[6];
  const float* w_hh1 = (const float*)d_in[7];
  const float* b_ih1 = (const float*)d_in[8];
  const float* b_hh1 = (const float*)d_in[9];
  const float* fc_w  = (const float*)d_in[10];
  const float* fc_b  = (const float*)d_in[11];
  float* out = (float*)d_out;
  float* ws  = (float*)d_ws;

  hipLaunchKernelGGL(prep_kernel, dim3(1024), dim3(256), 0, stream,
                     w_ih0, w_hh0, b_ih0, b_hh0, w_ih1, w_hh1, b_ih1, b_hh1, ws);
  for (int chunk = 0; chunk < 4; ++chunk) {
    int t0 = chunk * Tc;
    hipLaunchKernelGGL(lstm_l0, dim3(86), dim3(512), 0, stream, ws, x, lens, t0);
    hipLaunchKernelGGL(lstm_l1, dim3(86), dim3(512), 0, stream, ws, lens, t0);
  }
  hipLaunchKernelGGL(fc_kernel, dim3(256), dim3(256), 0, stream,
                     ws, fc_w, fc_b, out);
}

// Round 5
// 8036.763 us; speedup vs baseline: 7.2504x; 1.7784x over previous
//
#include <hip/hip_runtime.h>
#include <hip/hip_fp16.h>

// B=256, T=512, F=16, H=256, L=2 LSTM + gather(len-1) + ReLU + FC(256->1).
//
// R5: weights in fp16, gate dot-products via v_dot2_f32_f16 (fp32 accum).
// Phase decomposition (no intra-kernel cross-block comm): per 128-step chunk
// run lstm_l0 then lstm_l1; each block owns G=3 batches, h in LDS, cell state
// in regs, weights streamed from L2 (per-CU BW is the wall -> bytes halved).
//
// fp32 ws region (float offsets):
#define OFF_IH0   0        // [16 k][256 u][4 g] fp32 (64 KB)
#define OFF_B0    16384    // [256][4] = b_ih0+b_hh0
#define OFF_B1    17408    // [256][4]
#define OFF_C0S   18432    // [258][256] layer-0 cell state
#define OFF_C1S   84480    // [258][256]
#define OFF_H1S   150528   // [258][256] layer-1 h state (fp32)
#define OFF_HLAST 216576   // [258][256]
#define FP_END    282624
// fp16 region (half offsets from ws+FP_END), packed [k-pair][256 u][4 g][2 k]:
#define H_HH0 0            // [128 p][256][4][2]
#define H_IH1 262144
#define H_HH1 524288
#define H_H0C 786432       // h0 chunk, fp16 [258 b][128 tc][256 u]
// end: 9240576 halves; total ws = 1.13 MB + 18.5 MB = 19.6 MB

#define Tc 128

typedef _Float16 v2h __attribute__((ext_vector_type(2)));

__device__ __forceinline__ unsigned packh2(float a, float b) {
  __half2 h = __floats2half2_rn(a, b);
  return *(unsigned*)&h;
}

// acc.{x,y,z,w} += dot2(w.gate{0..3}, h)   (w = 4 half2 gates of one k-pair)
__device__ __forceinline__ float4 dot4(const float4 w, const v2h h, float4 acc) {
  const v2h* wg = (const v2h*)&w;
  acc.x = __builtin_amdgcn_fdot2(wg[0], h, acc.x, false);
  acc.y = __builtin_amdgcn_fdot2(wg[1], h, acc.y, false);
  acc.z = __builtin_amdgcn_fdot2(wg[2], h, acc.z, false);
  acc.w = __builtin_amdgcn_fdot2(wg[3], h, acc.w, false);
  return acc;
}

__device__ __forceinline__ float sigf(float x) {
  return __fdividef(1.f, 1.f + __expf(-x));
}
__device__ __forceinline__ float tanhf_fast(float x) {
  float ax = fabsf(x);
  float e = __expf(-2.f * ax);
  float t = __fdividef(1.f - e, 1.f + e);
  return copysignf(t, x);
}
__device__ __forceinline__ float4 f4fma(float4 a, float4 w, float s) {
  a.x = fmaf(w.x, s, a.x);
  a.y = fmaf(w.y, s, a.y);
  a.z = fmaf(w.z, s, a.z);
  a.w = fmaf(w.w, s, a.w);
  return a;
}

// 512 blocks x 256 thr: idx in [0,131072): one half2 (k-pair) per matrix each.
__global__ __launch_bounds__(256) void prep_kernel(
    const float* __restrict__ w_ih0, const float* __restrict__ w_hh0,
    const float* __restrict__ b_ih0, const float* __restrict__ b_hh0,
    const float* __restrict__ w_ih1, const float* __restrict__ w_hh1,
    const float* __restrict__ b_ih1, const float* __restrict__ b_hh1,
    float* __restrict__ ws) {
  const int idx = blockIdx.x * blockDim.x + threadIdx.x;  // [0,131072)
  const int g = idx & 3, u = (idx >> 2) & 255, p = idx >> 10;  // p in [0,128)
  const int j = g * 256 + u;  // gate row in [0,1024)
  unsigned* h16u = (unsigned*)(ws + FP_END);
  h16u[H_HH0 / 2 + idx] = packh2(w_hh0[j * 256 + 2 * p], w_hh0[j * 256 + 2 * p + 1]);
  h16u[H_IH1 / 2 + idx] = packh2(w_ih1[j * 256 + 2 * p], w_ih1[j * 256 + 2 * p + 1]);
  h16u[H_HH1 / 2 + idx] = packh2(w_hh1[j * 256 + 2 * p], w_hh1[j * 256 + 2 * p + 1]);
  if (idx < 16384) {  // wih0 fp32: [k][u][g] with k = idx>>10 in [0,16)
    ws[OFF_IH0 + idx] = w_ih0[j * 16 + (idx >> 10)];
  }
  if (idx < 1024) {  // idx = u*4+g
    ws[OFF_B0 + idx] = b_ih0[j] + b_hh0[j];
    ws[OFF_B1 + idx] = b_ih1[j] + b_hh1[j];
  }
}

// ---------------- layer 0, one chunk ----------------
__global__ __launch_bounds__(512, 2) void lstm_l0(
    float* __restrict__ ws, const float* __restrict__ x,
    const int* __restrict__ lengths, int t0) {
  __shared__ __align__(16) __half hbuf[2][3 * 256];   // h0 fp16, dbuf
  __shared__ __align__(16) float xs[2][3][16];
  __shared__ float scratch[256 * 13];                  // stride 13: conflict-free
  const int tid = threadIdx.x;
  const int kh = tid >> 8;   // k-half: pairs [kh*64, kh*64+64)
  const int u = tid & 255;
  const int bg = blockIdx.x * 3;

  int len[3];
  #pragma unroll
  for (int b = 0; b < 3; ++b) len[b] = (bg + b < 256) ? lengths[bg + b] : 1;
  const int tmaxb = max(len[0], max(len[1], len[2]));
  if (t0 >= tmaxb) return;
  const int tend = min(Tc, tmaxb - t0);

  const __half* h16 = (const __half*)(ws + FP_END);
  unsigned short* h0cS = (unsigned short*)(h16 + H_H0C);
  const float4* wq = (const float4*)(h16 + H_HH0) + (size_t)kh * 64 * 256 + u;
  const float4* wih = (const float4*)(ws + OFF_IH0) + kh * 8 * 256 + u;
  const float4 bias = ((const float4*)(ws + OFF_B0))[u];

  float c[3] = {0.f, 0.f, 0.f};
  if (kh == 0) {  // init h0[t0-1] into hbuf[0] (fp16)
    #pragma unroll
    for (int b = 0; b < 3; ++b) {
      unsigned short hv = 0;
      if (t0 > 0) hv = h0cS[((size_t)(bg + b) * Tc + (Tc - 1)) * 256 + u];
      ((unsigned short*)hbuf[0])[b * 256 + u] = hv;
      if (t0 > 0) c[b] = ws[OFF_C0S + (bg + b) * 256 + u];
    }
  }
  if (tid < 48) {
    int b = tid >> 4, i = tid & 15;
    int bb = min(bg + b, 255);
    xs[0][b][i] = x[(size_t)bb * 8192 + t0 * 16 + i];
  }
  __syncthreads();

  for (int tc = 0; tc < tend; ++tc) {
    const int cur = tc & 1, nxt = cur ^ 1;
    float4 A0, A1, A2;
    if (kh == 0) { A0 = bias; A1 = bias; A2 = bias; }
    else { A0 = make_float4(0, 0, 0, 0); A1 = A0; A2 = A0; }

    // x-part: 8 k per half, fp32
    #pragma unroll
    for (int ii = 0; ii < 8; ++ii) {
      float4 w = wih[ii * 256];
      A0 = f4fma(A0, w, xs[cur][0][kh * 8 + ii]);
      A1 = f4fma(A1, w, xs[cur][1][kh * 8 + ii]);
      A2 = f4fma(A2, w, xs[cur][2][kh * 8 + ii]);
    }

    // h-part: 64 k-pairs per half via fdot2; 4-pair groups, 1-group prefetch
    {
      const float4* h0r0 = (const float4*)(hbuf[cur] + 0 * 256 + kh * 128);
      const float4* h0r1 = (const float4*)(hbuf[cur] + 1 * 256 + kh * 128);
      const float4* h0r2 = (const float4*)(hbuf[cur] + 2 * 256 + kh * 128);
      float4 wb[4], wn[4];
      #pragma unroll
      for (int p = 0; p < 4; ++p) wb[p] = wq[p * 256];
      for (int grp = 0; grp < 16; ++grp) {
        if (grp < 15) {
          #pragma unroll
          for (int p = 0; p < 4; ++p) wn[p] = wq[((grp + 1) * 4 + p) * 256];
        }
        float4 h40 = h0r0[grp], h41 = h0r1[grp], h42 = h0r2[grp];
        const v2h* hp0 = (const v2h*)&h40;
        const v2h* hp1 = (const v2h*)&h41;
        const v2h* hp2 = (const v2h*)&h42;
        #pragma unroll
        for (int p = 0; p < 4; ++p) {
          A0 = dot4(wb[p], hp0[p], A0);
          A1 = dot4(wb[p], hp1[p], A1);
          A2 = dot4(wb[p], hp2[p], A2);
        }
        #pragma unroll
        for (int p = 0; p < 4; ++p) wb[p] = wn[p];
      }
    }

    if (kh == 1) {
      #pragma unroll
      for (int g = 0; g < 4; ++g) {
        scratch[u * 13 + g] = ((const float*)&A0)[g];
        scratch[u * 13 + 4 + g] = ((const float*)&A1)[g];
        scratch[u * 13 + 8 + g] = ((const float*)&A2)[g];
      }
      if (tid < 256 + 48) {  // stage x[t+1]
        int bi = tid - 256, b = bi >> 4, i = bi & 15;
        int bb = min(bg + b, 255);
        int tn = min(t0 + tc + 1, 511);
        xs[nxt][b][i] = x[(size_t)bb * 8192 + tn * 16 + i];
      }
    }
    __syncthreads();

    if (kh == 0) {
      float4 B0, B1, B2;
      #pragma unroll
      for (int g = 0; g < 4; ++g) {
        ((float*)&B0)[g] = scratch[u * 13 + g];
        ((float*)&B1)[g] = scratch[u * 13 + 4 + g];
        ((float*)&B2)[g] = scratch[u * 13 + 8 + g];
      }
      A0 = f4fma(A0, B0, 1.f);
      A1 = f4fma(A1, B1, 1.f);
      A2 = f4fma(A2, B2, 1.f);
      float4 A[3] = {A0, A1, A2};
      #pragma unroll
      for (int b = 0; b < 3; ++b) {
        float ig = sigf(A[b].x), fg = sigf(A[b].y);
        float gg = tanhf_fast(A[b].z), og = sigf(A[b].w);
        c[b] = fg * c[b] + ig * gg;
        float h = og * tanhf_fast(c[b]);
        unsigned short hu = __half_as_ushort(__float2half(h));
        ((unsigned short*)hbuf[nxt])[b * 256 + u] = hu;
        h0cS[((size_t)(bg + b) * Tc + tc) * 256 + u] = hu;
      }
    }
    __syncthreads();
  }

  if (kh == 0) {
    #pragma unroll
    for (int b = 0; b < 3; ++b) ws[OFF_C0S + (bg + b) * 256 + u] = c[b];
  }
}

// ---------------- layer 1, one chunk ----------------
__global__ __launch_bounds__(512, 2) void lstm_l1(
    float* __restrict__ ws, const int* __restrict__ lengths, int t0) {
  __shared__ __align__(16) __half h1buf[2][3 * 256];
  __shared__ __align__(16) __half h0buf[2][3 * 256];
  __shared__ float scratch[256 * 13];
  const int tid = threadIdx.x;
  const int kh = tid >> 8;
  const int u = tid & 255;
  const int bg = blockIdx.x * 3;

  int len[3];
  #pragma unroll
  for (int b = 0; b < 3; ++b) len[b] = (bg + b < 256) ? lengths[bg + b] : 1;
  const int tmaxb = max(len[0], max(len[1], len[2]));
  if (t0 >= tmaxb) return;
  const int tend = min(Tc, tmaxb - t0);

  const __half* h16 = (const __half*)(ws + FP_END);
  const unsigned short* h0cS = (const unsigned short*)(h16 + H_H0C);
  const float4* wiP = (const float4*)(h16 + H_IH1) + (size_t)kh * 64 * 256 + u;
  const float4* whP = (const float4*)(h16 + H_HH1) + (size_t)kh * 64 * 256 + u;
  const float4 bias = ((const float4*)(ws + OFF_B1))[u];

  float c[3] = {0.f, 0.f, 0.f};
  float hout[3] = {0.f, 0.f, 0.f};
  if (kh == 0) {
    #pragma unroll
    for (int b = 0; b < 3; ++b) {
      // h1[t0-1] fp16 into h1buf[0]
      float hv = 0.f;
      if (t0 > 0) {
        hv = ws[OFF_H1S + (bg + b) * 256 + u];
        c[b] = ws[OFF_C1S + (bg + b) * 256 + u];
      }
      ((unsigned short*)h1buf[0])[b * 256 + u] = __half_as_ushort(__float2half(hv));
      // h0[t0] into h0buf[0]
      ((unsigned short*)h0buf[0])[b * 256 + u] =
          h0cS[((size_t)(bg + b) * Tc + 0) * 256 + u];
    }
  }
  __syncthreads();

  for (int tc = 0; tc < tend; ++tc) {
    const int cur = tc & 1, nxt = cur ^ 1;
    float4 A0, A1, A2;
    if (kh == 0) { A0 = bias; A1 = bias; A2 = bias; }
    else { A0 = make_float4(0, 0, 0, 0); A1 = A0; A2 = A0; }

    {
      const float4* h0r0 = (const float4*)(h0buf[cur] + 0 * 256 + kh * 128);
      const float4* h0r1 = (const float4*)(h0buf[cur] + 1 * 256 + kh * 128);
      const float4* h0r2 = (const float4*)(h0buf[cur] + 2 * 256 + kh * 128);
      const float4* h1r0 = (const float4*)(h1buf[cur] + 0 * 256 + kh * 128);
      const float4* h1r1 = (const float4*)(h1buf[cur] + 1 * 256 + kh * 128);
      const float4* h1r2 = (const float4*)(h1buf[cur] + 2 * 256 + kh * 128);
      float4 wib[4], whb[4], win[4], whn[4];
      #pragma unroll
      for (int p = 0; p < 4; ++p) { wib[p] = wiP[p * 256]; whb[p] = whP[p * 256]; }
      for (int grp = 0; grp < 16; ++grp) {
        if (grp < 15) {
          #pragma unroll
          for (int p = 0; p < 4; ++p) {
            win[p] = wiP[((grp + 1) * 4 + p) * 256];
            whn[p] = whP[((grp + 1) * 4 + p) * 256];
          }
        }
        float4 a0 = h0r0[grp], a1 = h0r1[grp], a2 = h0r2[grp];
        float4 b0 = h1r0[grp], b1 = h1r1[grp], b2 = h1r2[grp];
        const v2h* p00 = (const v2h*)&a0;
        const v2h* p01 = (const v2h*)&a1;
        const v2h* p02 = (const v2h*)&a2;
        const v2h* p10 = (const v2h*)&b0;
        const v2h* p11 = (const v2h*)&b1;
        const v2h* p12 = (const v2h*)&b2;
        #pragma unroll
        for (int p = 0; p < 4; ++p) {
          A0 = dot4(wib[p], p00[p], A0);
          A1 = dot4(wib[p], p01[p], A1);
          A2 = dot4(wib[p], p02[p], A2);
          A0 = dot4(whb[p], p10[p], A0);
          A1 = dot4(whb[p], p11[p], A1);
          A2 = dot4(whb[p], p12[p], A2);
        }
        #pragma unroll
        for (int p = 0; p < 4; ++p) { wib[p] = win[p]; whb[p] = whn[p]; }
      }
    }

    if (kh == 1) {
      #pragma unroll
      for (int g = 0; g < 4; ++g) {
        scratch[u * 13 + g] = ((const float*)&A0)[g];
        scratch[u * 13 + 4 + g] = ((const float*)&A1)[g];
        scratch[u * 13 + 8 + g] = ((const float*)&A2)[g];
      }
      // stage h0[t+1] (raw fp16 copy)
      if (tc + 1 < tend) {
        #pragma unroll
        for (int b = 0; b < 3; ++b)
          ((unsigned short*)h0buf[nxt])[b * 256 + u] =
              h0cS[((size_t)(bg + b) * Tc + tc + 1) * 256 + u];
      }
    }
    __syncthreads();

    if (kh == 0) {
      float4 B0, B1, B2;
      #pragma unroll
      for (int g = 0; g < 4; ++g) {
        ((float*)&B0)[g] = scratch[u * 13 + g];
        ((float*)&B1)[g] = scratch[u * 13 + 4 + g];
        ((float*)&B2)[g] = scratch[u * 13 + 8 + g];
      }
      A0 = f4fma(A0, B0, 1.f);
      A1 = f4fma(A1, B1, 1.f);
      A2 = f4fma(A2, B2, 1.f);
      float4 A[3] = {A0, A1, A2};
      const int t = t0 + tc;
      #pragma unroll
      for (int b = 0; b < 3; ++b) {
        float ig = sigf(A[b].x), fg = sigf(A[b].y);
        float gg = tanhf_fast(A[b].z), og = sigf(A[b].w);
        c[b] = fg * c[b] + ig * gg;
        float h = og * tanhf_fast(c[b]);
        hout[b] = h;
        ((unsigned short*)h1buf[nxt])[b * 256 + u] =
            __half_as_ushort(__float2half(h));
        if (t == len[b] - 1) ws[OFF_HLAST + (bg + b) * 256 + u] = h;
      }
    }
    __syncthreads();
  }

  if (kh == 0) {
    #pragma unroll
    for (int b = 0; b < 3; ++b) {
      ws[OFF_C1S + (bg + b) * 256 + u] = c[b];
      ws[OFF_H1S + (bg + b) * 256 + u] = hout[b];
    }
  }
}

// ---------------- FC epilogue ----------------
__global__ __launch_bounds__(256) void fc_kernel(
    const float* __restrict__ ws, const float* __restrict__ fc_w,
    const float* __restrict__ fc_b, float* __restrict__ out) {
  __shared__ float red[256];
  const int tid = threadIdx.x;
  const int b = blockIdx.x;
  red[tid] = fmaxf(ws[OFF_HLAST + b * 256 + tid], 0.f) * fc_w[tid];
  __syncthreads();
  #pragma unroll
  for (int s = 128; s > 0; s >>= 1) {
    if (tid < s) red[tid] += red[tid + s];
    __syncthreads();
  }
  if (tid == 0) out[b] = red[0] + fc_b[0];
}

extern "C" void kernel_launch(void* const* d_in, const int* in_sizes, int n_in,
                              void* d_out, int out_size, void* d_ws, size_t ws_size,
                              hipStream_t stream) {
  const float* x     = (const float*)d_in[0];
  const int*   lens  = (const int*)d_in[1];
  const float* w_ih0 = (const float*)d_in[2];
  const float* w_hh0 = (const float*)d_in[3];
  const float* b_ih0 = (const float*)d_in[4];
  const float* b_hh0 = (const float*)d_in[5];
  const float* w_ih1 = (const float*)d_in[6];
  const float* w_hh1 = (const float*)d_in[7];
  const float* b_ih1 = (const float*)d_in[8];
  const float* b_hh1 = (const float*)d_in[9];
  const float* fc_w  = (const float*)d_in[10];
  const float* fc_b  = (const float*)d_in[11];
  float* out = (float*)d_out;
  float* ws  = (float*)d_ws;

  hipLaunchKernelGGL(prep_kernel, dim3(512), dim3(256), 0, stream,
                     w_ih0, w_hh0, b_ih0, b_hh0, w_ih1, w_hh1, b_ih1, b_hh1, ws);
  for (int chunk = 0; chunk < 4; ++chunk) {
    int t0 = chunk * Tc;
    hipLaunchKernelGGL(lstm_l0, dim3(86), dim3(512), 0, stream, ws, x, lens, t0);
    hipLaunchKernelGGL(lstm_l1, dim3(86), dim3(512), 0, stream, ws, lens, t0);
  }
  hipLaunchKernelGGL(fc_kernel, dim3(256), dim3(256), 0, stream,
                     ws, fc_w, fc_b, out);
}

// Round 6
// 3135.309 us; speedup vs baseline: 18.5851x; 2.5633x over previous
//
#include <hip/hip_runtime.h>
#include <hip/hip_fp16.h>

// B=256, T=512, F=16, H=256, L=2 LSTM + gather(len-1) + ReLU + FC(256->1).
//
// R6: 3-role pipelined launches. Launch k runs on disjoint blocks:
//   blocks   0..85 : l0 recurrence, chunk k      (streams w_hh0, 512 KB/step)
//   blocks  86..171: l1 recurrence, chunk k-2    (streams w_hh1 + reads xp1)
//   blocks 172..235: gemm xp1 = W_ih1 @ h0 + b1, chunk k-1 (time-parallel)
// Tc=32, 16 chunks, 18 launches. Data crosses roles only at kernel
// boundaries (the only cross-XCD sync that proved cheap+correct).

#define Tc 32
#define NCHUNK 16

// fp32 region (float offsets)
#define OFF_IH0   0        // [16 k][256 u][4 g]
#define OFF_B0    16384    // [256 u][4 g] = b_ih0+b_hh0
#define OFF_B1    17408    // [256 u][4 g] = b_ih1+b_hh1
#define OFF_C0S   18432    // [258][256] l0 cell state
#define OFF_C1S   84480    // [258][256] l1 cell state
#define OFF_H1S   150528   // [258][256] l1 h state
#define OFF_HLAST 216576   // [258][256]
#define FP_END    282624
// fp16 region (half offsets from h16 = (half*)(ws+FP_END))
#define H_HH0  0           // [128 p][256 u][4 g][2 k]
#define H_HH1  262144      // same layout
#define H_IH1  524288      // same layout (gemm streams it)
#define H_H0C  786432      // [2 slot][258 b][32 t][256 u]
#define H0SLOT 2113536
#define H_XP1  5013504     // [2 slot][258 b][32 t][1024 (u*4+g)]
#define XPSLOT 8454144
// end 21921792 halves; total ws ~= 45.0 MB

#define SMEM_BYTES 66560   // gemm needs 65536 (hc2); l0/l1 ~18 KB

typedef _Float16 v2h __attribute__((ext_vector_type(2)));

__device__ __forceinline__ unsigned packh2(float a, float b) {
  __half2 h = __floats2half2_rn(a, b);
  return *(unsigned*)&h;
}
__device__ __forceinline__ float4 dot4(const float4 w, const v2h h, float4 acc) {
  const v2h* wg = (const v2h*)&w;
  acc.x = __builtin_amdgcn_fdot2(wg[0], h, acc.x, false);
  acc.y = __builtin_amdgcn_fdot2(wg[1], h, acc.y, false);
  acc.z = __builtin_amdgcn_fdot2(wg[2], h, acc.z, false);
  acc.w = __builtin_amdgcn_fdot2(wg[3], h, acc.w, false);
  return acc;
}
__device__ __forceinline__ float sigf(float x) {
  return __fdividef(1.f, 1.f + __expf(-x));
}
__device__ __forceinline__ float tanhf_fast(float x) {
  float ax = fabsf(x);
  float e = __expf(-2.f * ax);
  float t = __fdividef(1.f - e, 1.f + e);
  return copysignf(t, x);
}
__device__ __forceinline__ float4 f4fma(float4 a, float4 w, float s) {
  a.x = fmaf(w.x, s, a.x);
  a.y = fmaf(w.y, s, a.y);
  a.z = fmaf(w.z, s, a.z);
  a.w = fmaf(w.w, s, a.w);
  return a;
}
__device__ __forceinline__ float h2f(unsigned short s) {
  __half h = __builtin_bit_cast(__half, s);
  return __half2float(h);
}
__device__ __forceinline__ float4 cvt4(ushort4 v) {
  float4 r;
  r.x = h2f(v.x); r.y = h2f(v.y); r.z = h2f(v.z); r.w = h2f(v.w);
  return r;
}

__global__ __launch_bounds__(256) void prep_kernel(
    const float* __restrict__ w_ih0, const float* __restrict__ w_hh0,
    const float* __restrict__ b_ih0, const float* __restrict__ b_hh0,
    const float* __restrict__ w_ih1, const float* __restrict__ w_hh1,
    const float* __restrict__ b_ih1, const float* __restrict__ b_hh1,
    float* __restrict__ ws) {
  const int idx = blockIdx.x * blockDim.x + threadIdx.x;  // [0,131072)
  const int g = idx & 3, u = (idx >> 2) & 255, p = idx >> 10;
  const int j = g * 256 + u;  // gate row in [0,1024)
  unsigned* h16u = (unsigned*)(ws + FP_END);
  h16u[H_HH0 / 2 + idx] = packh2(w_hh0[j * 256 + 2 * p], w_hh0[j * 256 + 2 * p + 1]);
  h16u[H_HH1 / 2 + idx] = packh2(w_hh1[j * 256 + 2 * p], w_hh1[j * 256 + 2 * p + 1]);
  h16u[H_IH1 / 2 + idx] = packh2(w_ih1[j * 256 + 2 * p], w_ih1[j * 256 + 2 * p + 1]);
  if (idx < 16384) ws[OFF_IH0 + idx] = w_ih0[j * 16 + (idx >> 10)];
  if (idx < 1024) {
    ws[OFF_B0 + idx] = b_ih0[j] + b_hh0[j];
    ws[OFF_B1 + idx] = b_ih1[j] + b_hh1[j];
  }
}

__global__ __launch_bounds__(512) void fused_kernel(
    float* __restrict__ ws, const float* __restrict__ x,
    const int* __restrict__ lengths, int step) {
  extern __shared__ __align__(16) char smem_raw[];
  const int bid = blockIdx.x;
  const int tid = threadIdx.x;
  __half* h16 = (__half*)(ws + FP_END);
  unsigned short* h0cS = (unsigned short*)(h16 + H_H0C);
  unsigned short* xpS = (unsigned short*)(h16 + H_XP1);

  if (bid < 86) {
    // ================= role: layer-0 recurrence, chunk kc = step ==========
    if (step >= NCHUNK) return;
    const int kc = step;
    const int kh = tid >> 8, u = tid & 255;
    const int bg = bid * 3;
    unsigned short* hb = (unsigned short*)smem_raw;  // [2][768]
    float* xsp = (float*)(smem_raw + 4096);          // [2][3][16]
    float* scratch = (float*)(smem_raw + 4608);      // 256*13

    int len[3];
    #pragma unroll
    for (int b = 0; b < 3; ++b) len[b] = (bg + b < 256) ? lengths[bg + b] : 1;
    const int tmaxb = max(len[0], max(len[1], len[2]));
    if (kc * Tc >= tmaxb) return;
    const int tend = min(Tc, tmaxb - kc * Tc);
    const int slot = kc & 1, slotP = slot ^ 1;

    const float4* wq = (const float4*)(h16 + H_HH0) + (size_t)kh * 64 * 256 + u;
    const float4* wih = (const float4*)(ws + OFF_IH0) + kh * 8 * 256 + u;
    const float4 bias = ((const float4*)(ws + OFF_B0))[u];

    float c[3] = {0.f, 0.f, 0.f};
    if (kh == 0) {
      #pragma unroll
      for (int b = 0; b < 3; ++b) {
        unsigned short hv = 0;
        if (kc > 0) {
          hv = h0cS[(size_t)slotP * H0SLOT + ((size_t)(bg + b) * 32 + 31) * 256 + u];
          c[b] = ws[OFF_C0S + (bg + b) * 256 + u];
        }
        hb[0 * 768 + b * 256 + u] = hv;
      }
    }
    if (tid < 48) {
      int b = tid >> 4, i = tid & 15;
      int bb = min(bg + b, 255);
      xsp[0 * 48 + b * 16 + i] = x[(size_t)bb * 8192 + (kc * Tc) * 16 + i];
    }
    __syncthreads();

    for (int tc = 0; tc < tend; ++tc) {
      const int cur = tc & 1, nxt = cur ^ 1;
      float4 A0, A1, A2;
      if (kh == 0) { A0 = bias; A1 = bias; A2 = bias; }
      else { A0 = make_float4(0, 0, 0, 0); A1 = A0; A2 = A0; }

      // x-part: 8 k per half, fp32
      #pragma unroll
      for (int ii = 0; ii < 8; ++ii) {
        float4 w = wih[ii * 256];
        A0 = f4fma(A0, w, xsp[cur * 48 + 0 * 16 + kh * 8 + ii]);
        A1 = f4fma(A1, w, xsp[cur * 48 + 1 * 16 + kh * 8 + ii]);
        A2 = f4fma(A2, w, xsp[cur * 48 + 2 * 16 + kh * 8 + ii]);
      }
      // h-part: 64 k-pairs per half, 4-pair groups, 1-group prefetch
      {
        const float4* h0r0 = (const float4*)(hb + cur * 768 + 0 * 256 + kh * 128);
        const float4* h0r1 = (const float4*)(hb + cur * 768 + 1 * 256 + kh * 128);
        const float4* h0r2 = (const float4*)(hb + cur * 768 + 2 * 256 + kh * 128);
        float4 wb[4], wn[4];
        #pragma unroll
        for (int p = 0; p < 4; ++p) wb[p] = wq[p * 256];
        for (int grp = 0; grp < 16; ++grp) {
          if (grp < 15) {
            #pragma unroll
            for (int p = 0; p < 4; ++p) wn[p] = wq[((grp + 1) * 4 + p) * 256];
          }
          float4 h40 = h0r0[grp], h41 = h0r1[grp], h42 = h0r2[grp];
          const v2h* hp0 = (const v2h*)&h40;
          const v2h* hp1 = (const v2h*)&h41;
          const v2h* hp2 = (const v2h*)&h42;
          #pragma unroll
          for (int p = 0; p < 4; ++p) {
            A0 = dot4(wb[p], hp0[p], A0);
            A1 = dot4(wb[p], hp1[p], A1);
            A2 = dot4(wb[p], hp2[p], A2);
          }
          #pragma unroll
          for (int p = 0; p < 4; ++p) wb[p] = wn[p];
        }
      }
      if (kh == 1) {
        #pragma unroll
        for (int g = 0; g < 4; ++g) {
          scratch[u * 13 + g] = ((const float*)&A0)[g];
          scratch[u * 13 + 4 + g] = ((const float*)&A1)[g];
          scratch[u * 13 + 8 + g] = ((const float*)&A2)[g];
        }
        if (tid < 256 + 48) {  // stage x[t+1]
          int bi = tid - 256, b = bi >> 4, i = bi & 15;
          int bb = min(bg + b, 255);
          int tn = min(kc * Tc + tc + 1, 511);
          xsp[nxt * 48 + b * 16 + i] = x[(size_t)bb * 8192 + tn * 16 + i];
        }
      }
      __syncthreads();
      if (kh == 0) {
        float4 B0, B1, B2;
        #pragma unroll
        for (int g = 0; g < 4; ++g) {
          ((float*)&B0)[g] = scratch[u * 13 + g];
          ((float*)&B1)[g] = scratch[u * 13 + 4 + g];
          ((float*)&B2)[g] = scratch[u * 13 + 8 + g];
        }
        A0 = f4fma(A0, B0, 1.f);
        A1 = f4fma(A1, B1, 1.f);
        A2 = f4fma(A2, B2, 1.f);
        float4 A[3] = {A0, A1, A2};
        #pragma unroll
        for (int b = 0; b < 3; ++b) {
          float ig = sigf(A[b].x), fg = sigf(A[b].y);
          float gg = tanhf_fast(A[b].z), og = sigf(A[b].w);
          c[b] = fg * c[b] + ig * gg;
          float h = og * tanhf_fast(c[b]);
          unsigned short hu = __half_as_ushort(__float2half(h));
          hb[nxt * 768 + b * 256 + u] = hu;
          h0cS[(size_t)slot * H0SLOT + ((size_t)(bg + b) * 32 + tc) * 256 + u] = hu;
        }
      }
      __syncthreads();
    }
    if (kh == 0) {
      #pragma unroll
      for (int b = 0; b < 3; ++b) ws[OFF_C0S + (bg + b) * 256 + u] = c[b];
    }

  } else if (bid < 172) {
    // ============ role: layer-1 recurrence, chunk kc = step-2 =============
    if (step < 2 || step >= NCHUNK + 2) return;
    const int kc = step - 2;
    const int kh = tid >> 8, u = tid & 255;
    const int bg = (bid - 86) * 3;
    unsigned short* h1b = (unsigned short*)smem_raw;  // [2][768]
    float* scratch = (float*)(smem_raw + 4096);       // 256*13

    int len[3];
    #pragma unroll
    for (int b = 0; b < 3; ++b) len[b] = (bg + b < 256) ? lengths[bg + b] : 1;
    const int tmaxb = max(len[0], max(len[1], len[2]));
    if (kc * Tc >= tmaxb) return;
    const int tend = min(Tc, tmaxb - kc * Tc);
    const int slot = kc & 1;

    const float4* whP = (const float4*)(h16 + H_HH1) + (size_t)kh * 64 * 256 + u;

    float c[3] = {0.f, 0.f, 0.f}, hout[3] = {0.f, 0.f, 0.f};
    if (kh == 0) {
      #pragma unroll
      for (int b = 0; b < 3; ++b) {
        float hv = 0.f;
        if (kc > 0) {
          hv = ws[OFF_H1S + (bg + b) * 256 + u];
          c[b] = ws[OFF_C1S + (bg + b) * 256 + u];
        }
        h1b[0 * 768 + b * 256 + u] = __half_as_ushort(__float2half(hv));
      }
    }
    const unsigned short* xb =
        xpS + (size_t)slot * XPSLOT + (size_t)bg * 32768 + u * 4;
    ushort4 xc0, xc1, xc2;
    if (kh == 0) {
      xc0 = *(const ushort4*)(xb);
      xc1 = *(const ushort4*)(xb + 32768);
      xc2 = *(const ushort4*)(xb + 65536);
    }
    __syncthreads();

    for (int tc = 0; tc < tend; ++tc) {
      const int cur = tc & 1, nxt = cur ^ 1;
      float4 A0, A1, A2;
      ushort4 xn0, xn1, xn2;
      if (kh == 0) {
        A0 = cvt4(xc0); A1 = cvt4(xc1); A2 = cvt4(xc2);  // xp1 (bias folded)
        if (tc + 1 < tend) {  // prefetch next step's xp1 (L3 latency)
          xn0 = *(const ushort4*)(xb + (tc + 1) * 1024);
          xn1 = *(const ushort4*)(xb + 32768 + (tc + 1) * 1024);
          xn2 = *(const ushort4*)(xb + 65536 + (tc + 1) * 1024);
        }
      } else { A0 = make_float4(0, 0, 0, 0); A1 = A0; A2 = A0; }

      {
        const float4* r0 = (const float4*)(h1b + cur * 768 + 0 * 256 + kh * 128);
        const float4* r1 = (const float4*)(h1b + cur * 768 + 1 * 256 + kh * 128);
        const float4* r2 = (const float4*)(h1b + cur * 768 + 2 * 256 + kh * 128);
        float4 wb[4], wn[4];
        #pragma unroll
        for (int p = 0; p < 4; ++p) wb[p] = whP[p * 256];
        for (int grp = 0; grp < 16; ++grp) {
          if (grp < 15) {
            #pragma unroll
            for (int p = 0; p < 4; ++p) wn[p] = whP[((grp + 1) * 4 + p) * 256];
          }
          float4 v0 = r0[grp], v1 = r1[grp], v2 = r2[grp];
          const v2h* q0 = (const v2h*)&v0;
          const v2h* q1 = (const v2h*)&v1;
          const v2h* q2 = (const v2h*)&v2;
          #pragma unroll
          for (int p = 0; p < 4; ++p) {
            A0 = dot4(wb[p], q0[p], A0);
            A1 = dot4(wb[p], q1[p], A1);
            A2 = dot4(wb[p], q2[p], A2);
          }
          #pragma unroll
          for (int p = 0; p < 4; ++p) wb[p] = wn[p];
        }
      }
      if (kh == 1) {
        #pragma unroll
        for (int g = 0; g < 4; ++g) {
          scratch[u * 13 + g] = ((const float*)&A0)[g];
          scratch[u * 13 + 4 + g] = ((const float*)&A1)[g];
          scratch[u * 13 + 8 + g] = ((const float*)&A2)[g];
        }
      }
      __syncthreads();
      if (kh == 0) {
        float4 B0, B1, B2;
        #pragma unroll
        for (int g = 0; g < 4; ++g) {
          ((float*)&B0)[g] = scratch[u * 13 + g];
          ((float*)&B1)[g] = scratch[u * 13 + 4 + g];
          ((float*)&B2)[g] = scratch[u * 13 + 8 + g];
        }
        A0 = f4fma(A0, B0, 1.f);
        A1 = f4fma(A1, B1, 1.f);
        A2 = f4fma(A2, B2, 1.f);
        float4 A[3] = {A0, A1, A2};
        const int t = kc * Tc + tc;
        #pragma unroll
        for (int b = 0; b < 3; ++b) {
          float ig = sigf(A[b].x), fg = sigf(A[b].y);
          float gg = tanhf_fast(A[b].z), og = sigf(A[b].w);
          c[b] = fg * c[b] + ig * gg;
          float h = og * tanhf_fast(c[b]);
          hout[b] = h;
          h1b[nxt * 768 + b * 256 + u] = __half_as_ushort(__float2half(h));
          if (t == len[b] - 1) ws[OFF_HLAST + (bg + b) * 256 + u] = h;
        }
        xc0 = xn0; xc1 = xn1; xc2 = xn2;
      }
      __syncthreads();
    }
    if (kh == 0) {
      #pragma unroll
      for (int b = 0; b < 3; ++b) {
        ws[OFF_C1S + (bg + b) * 256 + u] = c[b];
        ws[OFF_H1S + (bg + b) * 256 + u] = hout[b];
      }
    }

  } else {
    // ===== role: gemm xp1 = W_ih1 @ h0 + b1, chunk kc = step-1 ============
    if (step < 1 || step >= NCHUNK + 1) return;
    if (bid >= 236) return;
    const int kc = step - 1;
    const int gid = bid - 172;  // [0,64)
    const int b0g = gid * 4;    // 4 batches per block
    const int rt = tid & 63, wv = tid >> 6;  // wv = wave index (col tile)
    __half2* hc2 = (__half2*)smem_raw;       // [128 p][128 col]

    int lmax = 0;
    #pragma unroll
    for (int i = 0; i < 4; ++i) lmax = max(lmax, lengths[b0g + i]);
    if (kc * Tc >= lmax) return;
    const int slot = kc & 1;

    // stage hc2[p][col] = (h0[col][2p], h0[col][2p+1]); col = b*32 + t
    {
      const unsigned short* src =
          h0cS + (size_t)slot * H0SLOT + (size_t)b0g * 8192;
      const int cl = tid & 127, pg = tid >> 7;  // p range pg*32 .. +31
      #pragma unroll
      for (int pp = 0; pp < 32; pp += 4) {
        const int p0 = pg * 32 + pp;
        uint4 v = *(const uint4*)(src + (size_t)cl * 256 + p0 * 2);
        unsigned* d = (unsigned*)hc2;
        d[(p0 + 0) * 128 + cl] = v.x;
        d[(p0 + 1) * 128 + cl] = v.y;
        d[(p0 + 2) * 128 + cl] = v.z;
        d[(p0 + 3) * 128 + cl] = v.w;
      }
    }
    __syncthreads();

    const __half* Wb = h16 + H_IH1;  // [p][u][g][2]
    unsigned short* xdst = xpS + (size_t)slot * XPSLOT;
    #pragma unroll 1
    for (int rp = 0; rp < 2; ++rp) {
      #pragma unroll 1
      for (int cp = 0; cp < 2; ++cp) {
        const int uA = rp * 128 + rt, uB = uA + 64;
        const int c0 = cp * 64 + wv * 8;
        const float4 bA = ((const float4*)(ws + OFF_B1))[uA];
        const float4 bB = ((const float4*)(ws + OFF_B1))[uB];
        float accA[4][8], accB[4][8];
        #pragma unroll
        for (int g = 0; g < 4; ++g)
          #pragma unroll
          for (int cc = 0; cc < 8; ++cc) {
            accA[g][cc] = ((const float*)&bA)[g];
            accB[g][cc] = ((const float*)&bB)[g];
          }
        #pragma unroll 2
        for (int p = 0; p < 128; ++p) {
          float4 wA = *(const float4*)(Wb + (size_t)p * 2048 + uA * 8);
          float4 wB = *(const float4*)(Wb + (size_t)p * 2048 + uB * 8);
          float4 h0v = *(const float4*)(hc2 + p * 128 + c0);      // cols 0..3
          float4 h1v = *(const float4*)(hc2 + p * 128 + c0 + 4);  // cols 4..7
          const v2h* ga = (const v2h*)&wA;
          const v2h* gb = (const v2h*)&wB;
          const v2h* hv = (const v2h*)&h0v;
          const v2h* hw = (const v2h*)&h1v;
          #pragma unroll
          for (int g = 0; g < 4; ++g) {
            #pragma unroll
            for (int cc = 0; cc < 4; ++cc) {
              accA[g][cc] = __builtin_amdgcn_fdot2(ga[g], hv[cc], accA[g][cc], false);
              accA[g][cc + 4] = __builtin_amdgcn_fdot2(ga[g], hw[cc], accA[g][cc + 4], false);
              accB[g][cc] = __builtin_amdgcn_fdot2(gb[g], hv[cc], accB[g][cc], false);
              accB[g][cc + 4] = __builtin_amdgcn_fdot2(gb[g], hw[cc], accB[g][cc + 4], false);
            }
          }
        }
        #pragma unroll
        for (int cc = 0; cc < 8; ++cc) {
          const int col = c0 + cc;
          const size_t cb = ((size_t)(b0g + (col >> 5)) * 32 + (col & 31)) * 1024;
          ushort4 oA, oB;
          oA.x = __half_as_ushort(__float2half(accA[0][cc]));
          oA.y = __half_as_ushort(__float2half(accA[1][cc]));
          oA.z = __half_as_ushort(__float2half(accA[2][cc]));
          oA.w = __half_as_ushort(__float2half(accA[3][cc]));
          oB.x = __half_as_ushort(__float2half(accB[0][cc]));
          oB.y = __half_as_ushort(__float2half(accB[1][cc]));
          oB.z = __half_as_ushort(__float2half(accB[2][cc]));
          oB.w = __half_as_ushort(__float2half(accB[3][cc]));
          *(ushort4*)(xdst + cb + uA * 4) = oA;
          *(ushort4*)(xdst + cb + uB * 4) = oB;
        }
      }
    }
  }
}

__global__ __launch_bounds__(256) void fc_kernel(
    const float* __restrict__ ws, const float* __restrict__ fc_w,
    const float* __restrict__ fc_b, float* __restrict__ out) {
  __shared__ float red[256];
  const int tid = threadIdx.x;
  const int b = blockIdx.x;
  red[tid] = fmaxf(ws[OFF_HLAST + b * 256 + tid], 0.f) * fc_w[tid];
  __syncthreads();
  #pragma unroll
  for (int s = 128; s > 0; s >>= 1) {
    if (tid < s) red[tid] += red[tid + s];
    __syncthreads();
  }
  if (tid == 0) out[b] = red[0] + fc_b[0];
}

extern "C" void kernel_launch(void* const* d_in, const int* in_sizes, int n_in,
                              void* d_out, int out_size, void* d_ws, size_t ws_size,
                              hipStream_t stream) {
  const float* x     = (const float*)d_in[0];
  const int*   lens  = (const int*)d_in[1];
  const float* w_ih0 = (const float*)d_in[2];
  const float* w_hh0 = (const float*)d_in[3];
  const float* b_ih0 = (const float*)d_in[4];
  const float* b_hh0 = (const float*)d_in[5];
  const float* w_ih1 = (const float*)d_in[6];
  const float* w_hh1 = (const float*)d_in[7];
  const float* b_ih1 = (const float*)d_in[8];
  const float* b_hh1 = (const float*)d_in[9];
  const float* fc_w  = (const float*)d_in[10];
  const float* fc_b  = (const float*)d_in[11];
  float* out = (float*)d_out;
  float* ws  = (float*)d_ws;

  hipLaunchKernelGGL(prep_kernel, dim3(512), dim3(256), 0, stream,
                     w_ih0, w_hh0, b_ih0, b_hh0, w_ih1, w_hh1, b_ih1, b_hh1, ws);
  hipFuncSetAttribute(reinterpret_cast<const void*>(fused_kernel),
                      hipFuncAttributeMaxDynamicSharedMemorySize, SMEM_BYTES);
  for (int k = 0; k < NCHUNK + 2; ++k) {
    hipLaunchKernelGGL(fused_kernel, dim3(236), dim3(512), SMEM_BYTES, stream,
                       ws, x, lens, k);
  }
  hipLaunchKernelGGL(fc_kernel, dim3(256), dim3(256), 0, stream,
                     ws, fc_w, fc_b, out);
}